// Round 12
// baseline (486.130 us; speedup 1.0000x reference)
//
#include <hip/hip_runtime.h>
#include <math.h>

#define CIN  32
#define COUT 64
#define KVOL 27
#define EPSF 1e-5f

typedef __attribute__((ext_vector_type(8))) short          short8;
typedef __attribute__((ext_vector_type(8))) unsigned short u16x8;
typedef __attribute__((ext_vector_type(4))) float          float4v;

__device__ __forceinline__ float eluf(float x) { return x > 0.f ? x : expm1f(x); }

// f32 -> bf16 round-to-nearest-even
__device__ __forceinline__ unsigned short f2bf(float x) {
    unsigned u = __float_as_uint(x);
    unsigned r = (u + 0x7FFFu + ((u >> 16) & 1u)) >> 16;
    return (unsigned short)r;
}
__device__ __forceinline__ unsigned pk2bf(float lo, float hi) {
    return (unsigned)f2bf(lo) | ((unsigned)f2bf(hi) << 16);
}
__device__ __forceinline__ float bf2f(unsigned short h) {
    return __uint_as_float(((unsigned)h) << 16);
}

// async global->LDS, 16B per lane. LDS dest = wave-uniform base + lane*16;
// global source is per-lane (gather + swizzle live on the source side).
__device__ __forceinline__ void gload_lds16(const unsigned short* src, unsigned short* dst) {
    __builtin_amdgcn_global_load_lds(
        (const __attribute__((address_space(1))) unsigned int*)(const void*)src,
        (__attribute__((address_space(3))) unsigned int*)(void*)dst, 16, 0, 0);
}

// ---------------------------------------------------------------------------
// mega prep: fused cvt_w (blocks 0..53) + bucket build (+ zero-row init in
// its first block) + nbr-map inversion + gemm_t (down-conv). gemm_t no longer
// needs a precomputed Wdt: each block builds its A-fragments straight from
// the f32 Wd (8KB, L2-resident) -> no cross-block dependency, one dispatch.
// ---------------------------------------------------------------------------
__global__ __launch_bounds__(256) void mega_kernel(
    const float* __restrict__ W1, const float* __restrict__ W2,
    unsigned short* __restrict__ Wt1, unsigned short* __restrict__ Wt2,
    const int* __restrict__ pool_seg, int* __restrict__ cnt,
    int* __restrict__ bucket, int N,
    const int* __restrict__ conv_out, const int* __restrict__ conv_in,
    int* __restrict__ nbrT, int L, int M, int nbB, int nbL,
    const float* __restrict__ feats, const float* __restrict__ Wd,
    unsigned short* __restrict__ t_bf, float* __restrict__ red0,
    unsigned short* __restrict__ down_bf, unsigned short* __restrict__ o1t,
    int gemmBase)
{
    __shared__ float red_s[64];
    __shared__ float red_q[64];
    __shared__ __align__(16) unsigned short xpose[4][16 * 64];
    int b = blockIdx.x, t = threadIdx.x;

    if (b < 54) {  // W1/W2 transpose-convert
        const float* W = (b < 27) ? W1 : W2;
        unsigned short* Wt = (b < 27) ? Wt1 : Wt2;
        int k = (b < 27) ? b : b - 27;
        const float* src = W + (size_t)k * (COUT * COUT);
        unsigned short* dst = Wt + (size_t)k * (COUT * COUT);
        for (int e = t; e < COUT * COUT; e += 256) {
            int i = e >> 6, c = e & 63;
            dst[c * COUT + i] = f2bf(src[e]);
        }
        return;
    }
    if (b < 54 + nbB) {  // bucket: pooling cell = 2x2x4 -> capacity 16
        if (b == 54) {   // zero rows for conv gather (row M)
            if (t < 64)            down_bf[(size_t)M * COUT + t] = 0;
            else if (t < 128)      o1t[(size_t)M * COUT + (t - 64)] = 0;
        }
        int j = (b - 54) * 256 + t;
        if (j < N) {
            int s = pool_seg[j];
            int pos = atomicAdd(&cnt[s], 1);
            bucket[(size_t)s * 16 + pos] = j;
        }
        return;
    }
    if (b < gemmBase) {  // nbr: invert (k, pairlist) into nbrT[k][M]
        int bb = b - 54 - nbB;
        int k = bb / nbL, blk = bb - k * nbL;
        int idx = blk * 256 + t;
        if (idx < L) {
            int e = k * L + idx;
            int j = conv_out[e];
            if (j < M) nbrT[(size_t)k * M + j] = conv_in[e];
        }
        return;
    }

    // ---- gemm_t role: t^T = Wd^T @ feats^T, persistent-grid over tiles ----
    int gb = b - gemmBase;
    if (t < 64) { red_s[t] = 0.f; red_q[t] = 0.f; }
    __syncthreads();

    int w = t >> 6, lane = t & 63, l15 = lane & 15, quad = lane >> 4;
    int p = lane >> 2, qq = lane & 3;

    // A-frags direct from f32 Wd: aw[mt][j] = Wd[(quad*8+j)*COUT + 16mt+l15]
    short8 aw[4];
    #pragma unroll
    for (int mt = 0; mt < 4; ++mt) {
        #pragma unroll
        for (int j = 0; j < 8; ++j)
            aw[mt][j] = (short)f2bf(Wd[(quad * 8 + j) * COUT + 16 * mt + l15]);
    }

    float s1[16], sq[16];
    #pragma unroll
    for (int e = 0; e < 16; ++e) { s1[e] = 0.f; sq[e] = 0.f; }

    int numTiles = (N + 15) >> 4;
    int stride = 1024 * 4;
    int tile = gb * 4 + w;

    float4 c0 = make_float4(0.f, 0.f, 0.f, 0.f), c1 = c0;
    {
        int pt = tile * 16 + l15;
        if (tile < numTiles && pt < N) {
            const float4* s = (const float4*)(feats + (size_t)pt * CIN + quad * 8);
            c0 = s[0]; c1 = s[1];
        }
    }

    while (tile < numTiles) {
        int nt = tile + stride;
        float4 n0 = make_float4(0.f, 0.f, 0.f, 0.f), n1 = n0;
        {
            int npt = nt * 16 + l15;
            if (nt < numTiles && npt < N) {
                const float4* s = (const float4*)(feats + (size_t)npt * CIN + quad * 8);
                n0 = s[0]; n1 = s[1];
            }
        }
        union { short8 v; unsigned u[4]; } bb;
        bb.u[0] = pk2bf(c0.x, c0.y);
        bb.u[1] = pk2bf(c0.z, c0.w);
        bb.u[2] = pk2bf(c1.x, c1.y);
        bb.u[3] = pk2bf(c1.z, c1.w);

        float4v acc[4];
        #pragma unroll
        for (int mt = 0; mt < 4; ++mt)
            acc[mt] = __builtin_amdgcn_mfma_f32_16x16x32_bf16(
                aw[mt], bb.v, (float4v){0.f, 0.f, 0.f, 0.f}, 0, 0, 0);

        // wave-local transpose: chunk c = mt*4+quad (8B) at slot c^l15 of row l15
        {
            char* xb = (char*)xpose[w];
            #pragma unroll
            for (int mt = 0; mt < 4; ++mt) {
                uint2 o;
                o.x = pk2bf(acc[mt][0], acc[mt][1]);
                o.y = pk2bf(acc[mt][2], acc[mt][3]);
                *(uint2*)(xb + l15 * 128 + (((mt * 4 + quad) ^ l15) * 8)) = o;
            }
            int pt2 = tile * 16 + p;
            if (pt2 < N) {
                uint2 d0 = *(uint2*)(xb + p * 128 + (((qq * 4 + 0) ^ p) * 8));
                uint2 d1 = *(uint2*)(xb + p * 128 + (((qq * 4 + 1) ^ p) * 8));
                uint2 d2 = *(uint2*)(xb + p * 128 + (((qq * 4 + 2) ^ p) * 8));
                uint2 d3 = *(uint2*)(xb + p * 128 + (((qq * 4 + 3) ^ p) * 8));
                uint4 o0 = make_uint4(d0.x, d0.y, d1.x, d1.y);
                uint4 o1 = make_uint4(d2.x, d2.y, d3.x, d3.y);
                *(uint4*)(t_bf + (size_t)pt2 * COUT + qq * 16) = o0;
                *(uint4*)(t_bf + (size_t)pt2 * COUT + qq * 16 + 8) = o1;
            }
        }

        #pragma unroll
        for (int mt = 0; mt < 4; ++mt)
            #pragma unroll
            for (int e = 0; e < 4; ++e) {
                float v = acc[mt][e];
                s1[mt * 4 + e] += v; sq[mt * 4 + e] += v * v;
            }
        c0 = n0; c1 = n1;
        tile = nt;
    }

    #pragma unroll
    for (int m = 1; m <= 8; m <<= 1) {
        #pragma unroll
        for (int e = 0; e < 16; ++e) {
            s1[e] += __shfl_xor(s1[e], m);
            sq[e] += __shfl_xor(sq[e], m);
        }
    }
    if (l15 == 0) {
        #pragma unroll
        for (int e = 0; e < 16; ++e) {
            int ch = (e >> 2) * 16 + quad * 4 + (e & 3);
            atomicAdd(&red_s[ch], s1[e]);
            atomicAdd(&red_q[ch], sq[e]);
        }
    }
    __syncthreads();
    float* dst = red0 + (size_t)(gb & 3) * 128;
    if (t < 64)       atomicAdd(&dst[t], red_s[t]);
    else if (t < 128) atomicAdd(&dst[t], red_q[t - 64]);
}

// ---------------------------------------------------------------------------
// Gather-only pool with inlined BN0 finalize; bucket+cnt LDS-staged per block.
// ---------------------------------------------------------------------------
__global__ __launch_bounds__(256) void pool_max_kernel(
    const unsigned short* __restrict__ t_bf,
    const int* __restrict__ cnt, const int* __restrict__ bucket,
    const float* __restrict__ red0, const float* __restrict__ g0,
    const float* __restrict__ b0,
    unsigned short* __restrict__ down_bf, int M, int N)
{
    __shared__ float sc_s[64], sh_s[64];
    __shared__ int bkt_s[16][16];
    __shared__ int cnt_s[16];
    int t = threadIdx.x;
    if (t < 64) {
        float s = 0.f, q2 = 0.f;
        #pragma unroll
        for (int i = 0; i < 4; ++i) { s += red0[i * 128 + t]; q2 += red0[i * 128 + 64 + t]; }
        float m = s / (float)N;
        float var = q2 / (float)N - m * m;
        float sc = g0[t] / sqrtf(var + EPSF);
        sc_s[t] = sc;
        sh_s[t] = b0[t] - m * sc;
    }
    // stage this block's 16 segments' bucket rows (1KB) + cnts, coalesced
    int sb0 = blockIdx.x * 16;
    {
        int j = sb0 * 16 + t;           // 256 consecutive ints
        ((int*)bkt_s)[t] = (j < M * 16) ? bucket[j] : 0;
        if (t < 16) cnt_s[t] = (sb0 + t < M) ? cnt[sb0 + t] : 0;
    }
    __syncthreads();

    int sl = t >> 4, cg = t & 15;
    int s = sb0 + sl;
    if (s >= M) return;
    int n = cnt_s[sl];
    float4 mx = make_float4(-INFINITY, -INFINITY, -INFINITY, -INFINITY);
    float4 mn = make_float4( INFINITY,  INFINITY,  INFINITY,  INFINITY);
    for (int p = 0; p < n; ++p) {
        int idx = bkt_s[sl][p];
        ushort4 v = *(const ushort4*)(t_bf + (size_t)idx * COUT + cg * 4);
        float f0 = bf2f(v.x), f1 = bf2f(v.y), f2 = bf2f(v.z), f3 = bf2f(v.w);
        mx.x = fmaxf(mx.x, f0); mn.x = fminf(mn.x, f0);
        mx.y = fmaxf(mx.y, f1); mn.y = fminf(mn.y, f1);
        mx.z = fmaxf(mx.z, f2); mn.z = fminf(mn.z, f2);
        mx.w = fmaxf(mx.w, f3); mn.w = fminf(mn.w, f3);
    }
    int c0 = cg * 4;
    float scx = sc_s[c0], scy = sc_s[c0 + 1], scz = sc_s[c0 + 2], scw = sc_s[c0 + 3];
    float shx = sh_s[c0], shy = sh_s[c0 + 1], shz = sh_s[c0 + 2], shw = sh_s[c0 + 3];
    ushort4 o;
    o.x = f2bf(eluf(scx * (scx >= 0.f ? mx.x : mn.x) + shx));
    o.y = f2bf(eluf(scy * (scy >= 0.f ? mx.y : mn.y) + shy));
    o.z = f2bf(eluf(scz * (scz >= 0.f ? mx.z : mn.z) + shz));
    o.w = f2bf(eluf(scw * (scw >= 0.f ? mx.w : mn.w) + shw));
    *(ushort4*)(down_bf + (size_t)s * COUT + c0) = o;
}

// o1t = bf16( ELU(scale1*o1b + shift1) ), bf16 in, inlined BN finalize.
__global__ __launch_bounds__(256) void bn_elu_cvt_kernel(
    const unsigned short* __restrict__ o1b, const float* __restrict__ red,
    const float* __restrict__ g, const float* __restrict__ bb,
    unsigned short* __restrict__ o1t, int n4, int M)
{
    __shared__ float sc_s[64], sh_s[64];
    int t = threadIdx.x;
    if (t < 64) {
        float m = red[t] / (float)M;
        float var = red[64 + t] / (float)M - m * m;
        float sc = g[t] / sqrtf(var + EPSF);
        sc_s[t] = sc;
        sh_s[t] = bb[t] - m * sc;
    }
    __syncthreads();
    int i = blockIdx.x * 256 + t;
    if (i < n4) {
        ushort4 v = ((const ushort4*)o1b)[i];
        int c0 = (i & 15) * 4;
        ushort4 o;
        o.x = f2bf(eluf(bf2f(v.x) * sc_s[c0]     + sh_s[c0]));
        o.y = f2bf(eluf(bf2f(v.y) * sc_s[c0 + 1] + sh_s[c0 + 1]));
        o.z = f2bf(eluf(bf2f(v.z) * sc_s[c0 + 2] + sh_s[c0 + 2]));
        o.w = f2bf(eluf(bf2f(v.w) * sc_s[c0 + 3] + sh_s[c0 + 3]));
        ((ushort4*)o1t)[i] = o;
    }
}

// out = elu( elu(scale2*raw + shift2) + down ), bf16 raw in, inlined finalize.
__global__ __launch_bounds__(256) void final_kernel(
    float* __restrict__ out, const unsigned short* __restrict__ o2b,
    const unsigned short* __restrict__ down_bf,
    const float* __restrict__ red, const float* __restrict__ g,
    const float* __restrict__ bb, int n4, int M)
{
    __shared__ float sc_s[64], sh_s[64];
    int t = threadIdx.x;
    if (t < 64) {
        float m = red[t] / (float)M;
        float var = red[64 + t] / (float)M - m * m;
        float sc = g[t] / sqrtf(var + EPSF);
        sc_s[t] = sc;
        sh_s[t] = bb[t] - m * sc;
    }
    __syncthreads();
    int i = blockIdx.x * 256 + t;
    if (i < n4) {
        ushort4 v = ((const ushort4*)o2b)[i];
        ushort4 d = ((const ushort4*)down_bf)[i];
        int c0 = (i & 15) * 4;
        float4 o;
        o.x = eluf(eluf(bf2f(v.x) * sc_s[c0]     + sh_s[c0])     + bf2f(d.x));
        o.y = eluf(eluf(bf2f(v.y) * sc_s[c0 + 1] + sh_s[c0 + 1]) + bf2f(d.y));
        o.z = eluf(eluf(bf2f(v.z) * sc_s[c0 + 2] + sh_s[c0 + 2]) + bf2f(d.z));
        o.w = eluf(eluf(bf2f(v.w) * sc_s[c0 + 3] + sh_s[c0 + 3]) + bf2f(d.w));
        ((float4*)out)[i] = o;
    }
}

// ---------------------------------------------------------------------------
// MFMA implicit-GEMM sparse conv. = round-10 best (v9), REVERTED VERBATIM:
// async staging via global_load_lds (no dest regs -> loads stay in flight
// across compute), source-side XOR swizzle, wave-linear LDS dest, zero row M
// for missing neighbors, 256x64 tile, 512 thr, 80KB LDS (2 blocks/CU),
// XCD-chunked block swizzle, fused BN stats, raw bf16 output. Rounds 6-8 and
// 11 proved: reg-prefetch collapses (compiler sinks loads) and counted-vmcnt
// dual-barrier schedules regress (-7us) -- this single-__syncthreads form is
// the measured optimum (~92-97us).
// ---------------------------------------------------------------------------
__global__ __launch_bounds__(512, 4) void conv_mfma_kernel(
    const unsigned short* __restrict__ in,   // (M+1) x 64, row M = zeros
    const unsigned short* __restrict__ Wt,
    const int* __restrict__ nbrT, int M,
    unsigned short* __restrict__ outb, float* __restrict__ red_out)
{
    __shared__ __align__(16) unsigned short A_lds[2][256 * 64];  // 64 KB
    __shared__ __align__(16) unsigned short W_lds[2][64 * 64];   // 16 KB
    int t = threadIdx.x;

    // XCD-chunked bijective remap (m204)
    int nwg = gridDim.x;
    int q = nwg >> 3, r = nwg & 7;
    int xcd = blockIdx.x & 7, pos = blockIdx.x >> 3;
    int sb = (xcd < r ? xcd * (q + 1) : r * (q + 1) + (xcd - r) * q) + pos;
    int base = sb * 256;

    int w = t >> 6, lane = t & 63, l15 = lane & 15, quad = lane >> 4;
    int ar8 = lane >> 3, ac = lane & 7;  // staging: 8 lanes/row, slot ac

    float4v acc[2][4];
    #pragma unroll
    for (int s = 0; s < 2; ++s)
        #pragma unroll
        for (int n = 0; n < 4; ++n)
            acc[s][n] = (float4v){0.f, 0.f, 0.f, 0.f};

    // resolve gather row (zero row M for missing/tail) for 4 A-chunks of this wave
    auto LOADIDX = [&](int k, int* e) {
        #pragma unroll
        for (int i = 0; i < 4; ++i) {
            int rr = (w << 5) + (i << 3) + ar8;
            int j = base + rr;
            int idx = nbrT[(size_t)k * M + (j < M ? j : 0)];
            e[i] = (j < M && idx >= 0) ? idx : M;
        }
    };
    // stage A (32KB) + W (8KB) for one k-offset into buffer buf, async.
    auto STAGE = [&](int buf, const int* e, int kw) {
        unsigned short* An = A_lds[buf];
        unsigned short* Wn = W_lds[buf];
        #pragma unroll
        for (int i = 0; i < 4; ++i) {
            int rr = (w << 5) + (i << 3) + ar8;
            gload_lds16(in + (size_t)e[i] * COUT + ((ac ^ (rr & 7)) * 8),
                        An + (w << 11) + (i << 9));
        }
        int wr = (w << 3) + ar8;
        gload_lds16(Wt + (size_t)kw * (COUT * COUT) + wr * COUT + ((ac ^ (wr & 7)) * 8),
                    Wn + (w << 9));
    };

    int eC[4], eN[4];
    LOADIDX(0, eC);
    STAGE(0, eC, 0);
    LOADIDX(1, eC);   // indices for k=1 (used next)
    __syncthreads();

    for (int k = 0; k < KVOL; ++k) {
        bool pf = (k + 1 < KVOL);
        if (pf) {
            STAGE((k + 1) & 1, eC, k + 1);            // async, in flight across compute
            if (k + 2 < KVOL) LOADIDX(k + 2, eN);     // indices for next STAGE
        }
        __builtin_amdgcn_sched_barrier(0);

        // ---- compute on buf[k&1] ----
        const unsigned short* Ab = A_lds[k & 1];
        const unsigned short* Wb = W_lds[k & 1];
        #pragma unroll
        for (int kk = 0; kk < 64; kk += 32) {
            int slb = quad + (kk >> 3);
            int r0 = 32 * w + l15;
            short8 a0 = *(const short8*)(Ab + r0 * 64 + ((slb ^ (r0 & 7)) * 8));
            int r1 = r0 + 16;
            short8 a1 = *(const short8*)(Ab + r1 * 64 + ((slb ^ (r1 & 7)) * 8));
            #pragma unroll
            for (int n = 0; n < 4; ++n) {
                int rb = 16 * n + l15;
                short8 b = *(const short8*)(Wb + rb * 64 + ((slb ^ (rb & 7)) * 8));
                acc[0][n] = __builtin_amdgcn_mfma_f32_16x16x32_bf16(a0, b, acc[0][n], 0, 0, 0);
                acc[1][n] = __builtin_amdgcn_mfma_f32_16x16x32_bf16(a1, b, acc[1][n], 0, 0, 0);
            }
        }

        if (pf) {
            #pragma unroll
            for (int i = 0; i < 4; ++i) eC[i] = eN[i];
        }
        __syncthreads();  // drains the in-flight global_load_lds + syncs buffers
    }

    // stores (C/D layout: col=lane&15, row=quad*4+reg), raw bf16
    #pragma unroll
    for (int s = 0; s < 2; ++s) {
        int row = base + 32 * w + 16 * s + quad * 4;
        #pragma unroll
        for (int n = 0; n < 4; ++n) {
            int c = 16 * n + l15;
            #pragma unroll
            for (int e = 0; e < 4; ++e)
                if (row + e < M)
                    outb[(size_t)(row + e) * COUT + c] = f2bf(acc[s][n][e]);
        }
    }

    // fused BN stats (rows >= M are exact zeros); scratch aliased into W_lds
    float* red_s = (float*)(W_lds[0]);
    float* red_q = red_s + 64;
    if (t < 128) red_s[t] = 0.f;
    __syncthreads();
    #pragma unroll
    for (int n = 0; n < 4; ++n) {
        float s1 = 0.f, sq = 0.f;
        #pragma unroll
        for (int s = 0; s < 2; ++s)
            #pragma unroll
            for (int e = 0; e < 4; ++e) { float v = acc[s][n][e]; s1 += v; sq += v * v; }
        s1 += __shfl_xor(s1, 16); sq += __shfl_xor(sq, 16);
        s1 += __shfl_xor(s1, 32); sq += __shfl_xor(sq, 32);
        if (quad == 0) {
            atomicAdd(&red_s[16 * n + l15], s1);
            atomicAdd(&red_q[16 * n + l15], sq);
        }
    }
    __syncthreads();
    if (t < 64)       atomicAdd(&red_out[t], red_s[t]);
    else if (t < 128) atomicAdd(&red_out[t], red_q[t - 64]);
}

extern "C" void kernel_launch(void* const* d_in, const int* in_sizes, int n_in,
                              void* d_out, int out_size, void* d_ws, size_t ws_size,
                              hipStream_t stream)
{
    (void)n_in; (void)ws_size;
    const float* feats    = (const float*)d_in[0];
    const float* Wd       = (const float*)d_in[1];
    const float* g0       = (const float*)d_in[2];
    const float* b0       = (const float*)d_in[3];
    const float* W1       = (const float*)d_in[4];
    const float* g1       = (const float*)d_in[5];
    const float* b1       = (const float*)d_in[6];
    const float* W2       = (const float*)d_in[7];
    const float* g2       = (const float*)d_in[8];
    const float* b2       = (const float*)d_in[9];
    const int*   pool_seg = (const int*)d_in[10];
    const int*   conv_in  = (const int*)d_in[11];
    const int*   conv_out = (const int*)d_in[12];

    int N = in_sizes[0] / CIN;
    int M = out_size / COUT;
    int L = in_sizes[11] / KVOL;

    char* ws = (char*)d_ws;
    size_t off = 0;
    auto alloc = [&](size_t bytes) -> void* {
        void* p = ws + off;
        off = (off + bytes + 255) & ~(size_t)255;
        return p;
    };
    unsigned short* down_bf = (unsigned short*)alloc((size_t)(M + 1) * COUT * 2);
    unsigned short* o1b     = (unsigned short*)alloc((size_t)M * COUT * 2);
    unsigned short* o1t     = (unsigned short*)alloc((size_t)(M + 1) * COUT * 2);
    unsigned short* o2b     = (unsigned short*)alloc((size_t)M * COUT * 2);
    unsigned short* t_bf    = (unsigned short*)alloc((size_t)N * COUT * 2);
    int*            nbrT    = (int*)alloc((size_t)KVOL * M * 4);
    unsigned short* Wt1     = (unsigned short*)alloc((size_t)KVOL * COUT * COUT * 2);
    unsigned short* Wt2     = (unsigned short*)alloc((size_t)KVOL * COUT * COUT * 2);
    int*            bucket  = (int*)alloc((size_t)(M + 16) * 16 * 4);
    int*            cnt     = (int*)alloc((size_t)M * 4);         // cnt and red are
    float*          red     = (float*)alloc((size_t)768 * 4);     // adjacent: 1 memset
    float* red0 = red, *red1 = red + 512, *red2 = red + 640;

    hipMemsetAsync(nbrT, 0xFF, (size_t)KVOL * M * 4, stream);     // -1 = missing nbr
    hipMemsetAsync(cnt, 0, (size_t)((char*)(red + 768) - (char*)cnt), stream);

    int nbB = (N + 255) / 256, nbL = (L + 255) / 256;
    int gemmBase = 54 + nbB + nbL * KVOL;
    mega_kernel<<<gemmBase + 1024, 256, 0, stream>>>(
        W1, W2, Wt1, Wt2, pool_seg, cnt, bucket, N,
        conv_out, conv_in, nbrT, L, M, nbB, nbL,
        feats, Wd, t_bf, red0, down_bf, o1t, gemmBase);
    pool_max_kernel<<<(M + 15) / 16, 256, 0, stream>>>(
        t_bf, cnt, bucket, red0, g0, b0, down_bf, M, N);

    int cblocks = (M + 255) / 256;
    int n4 = (M * COUT) / 4;
    // conv1: bf16 in (down), RAW bf16 out + BN1 stats
    conv_mfma_kernel<<<cblocks, 512, 0, stream>>>(down_bf, Wt1, nbrT, M, o1b, red1);
    // BN1+ELU elementwise (bf16 -> bf16)
    bn_elu_cvt_kernel<<<(n4 + 255) / 256, 256, 0, stream>>>(o1b, red1, g1, b1, o1t, n4, M);
    // conv2: RAW bf16 out + BN2 stats
    conv_mfma_kernel<<<cblocks, 512, 0, stream>>>(o1t, Wt2, nbrT, M, o2b, red2);
    // final: BN2+ELU + residual + ELU, f32 out
    final_kernel<<<(n4 + 255) / 256, 256, 0, stream>>>(
        (float*)d_out, o2b, down_bf, red2, g2, b2, n4, M);
}

// Round 13
// 471.838 us; speedup vs baseline: 1.0303x; 1.0303x over previous
//
#include <hip/hip_runtime.h>
#include <math.h>

#define CIN  32
#define COUT 64
#define KVOL 27
#define EPSF 1e-5f

typedef __attribute__((ext_vector_type(8))) short          short8;
typedef __attribute__((ext_vector_type(8))) unsigned short u16x8;
typedef __attribute__((ext_vector_type(4))) float          float4v;

__device__ __forceinline__ float eluf(float x) { return x > 0.f ? x : expm1f(x); }

// f32 -> bf16 round-to-nearest-even
__device__ __forceinline__ unsigned short f2bf(float x) {
    unsigned u = __float_as_uint(x);
    unsigned r = (u + 0x7FFFu + ((u >> 16) & 1u)) >> 16;
    return (unsigned short)r;
}
__device__ __forceinline__ unsigned pk2bf(float lo, float hi) {
    return (unsigned)f2bf(lo) | ((unsigned)f2bf(hi) << 16);
}
__device__ __forceinline__ float bf2f(unsigned short h) {
    return __uint_as_float(((unsigned)h) << 16);
}

// async global->LDS, 16B per lane. LDS dest = wave-uniform base + lane*16;
// global source is per-lane (gather + swizzle live on the source side).
__device__ __forceinline__ void gload_lds16(const unsigned short* src, unsigned short* dst) {
    __builtin_amdgcn_global_load_lds(
        (const __attribute__((address_space(1))) unsigned int*)(const void*)src,
        (__attribute__((address_space(3))) unsigned int*)(void*)dst, 16, 0, 0);
}

// ---------------------------------------------------------------------------
// prep: fused cvt_w (blocks 0..54) + bucket build (next nbB blocks) +
// nbr-map inversion (next nbL*KVOL blocks). All three are independent.
// (Round-12 lesson: merging gemm_t in as well REGRESSES -- the scatter-bound
// prep blocks gate the gemm blocks scheduled after them in one dispatch.)
// ---------------------------------------------------------------------------
__global__ void prep_kernel(const float* __restrict__ W1, const float* __restrict__ W2,
                            const float* __restrict__ Wd,
                            unsigned short* __restrict__ Wt1, unsigned short* __restrict__ Wt2,
                            unsigned short* __restrict__ Wdt,
                            const int* __restrict__ pool_seg, int* __restrict__ cnt,
                            int* __restrict__ bucket, int N,
                            const int* __restrict__ conv_out, const int* __restrict__ conv_in,
                            int* __restrict__ nbrT, int L, int M, int nbB, int nbL)
{
    int b = blockIdx.x, t = threadIdx.x;
    if (b < 55) {
        if (b == 54) {
            for (int e = t; e < CIN * COUT; e += 256) {
                int i = e >> 6, c = e & 63;
                Wdt[c * CIN + i] = f2bf(Wd[e]);
            }
            return;
        }
        const float* W = (b < 27) ? W1 : W2;
        unsigned short* Wt = (b < 27) ? Wt1 : Wt2;
        int k = (b < 27) ? b : b - 27;
        const float* src = W + (size_t)k * (COUT * COUT);
        unsigned short* dst = Wt + (size_t)k * (COUT * COUT);
        for (int e = t; e < COUT * COUT; e += 256) {
            int i = e >> 6, c = e & 63;
            dst[c * COUT + i] = f2bf(src[e]);
        }
        return;
    }
    b -= 55;
    if (b < nbB) {  // bucket: pooling cell = 2x2x4 -> capacity 16
        int j = b * 256 + t;
        if (j < N) {
            int s = pool_seg[j];
            int pos = atomicAdd(&cnt[s], 1);
            bucket[(size_t)s * 16 + pos] = j;
        }
        return;
    }
    b -= nbB;  // nbr: invert (k, pairlist) into nbrT[k][M]
    int k = b / nbL, blk = b - k * nbL;
    int idx = blk * 256 + t;
    if (idx < L) {
        int e = k * L + idx;
        int j = conv_out[e];
        if (j < M) nbrT[(size_t)k * M + j] = conv_in[e];
    }
}

// ---------------------------------------------------------------------------
// Transposed streaming down-conv: t^T = Wd^T @ feats^T, zero LDS in hot loop.
// Wave-local LDS transpose in the epilogue -> coalesced 2KB/wave t_bf stores.
// ---------------------------------------------------------------------------
__global__ __launch_bounds__(256) void gemm_t_kernel(
    const float* __restrict__ feats, const unsigned short* __restrict__ Wdt,
    int N, unsigned short* __restrict__ t_bf, float* __restrict__ red0)
{
    __shared__ float red_s[64];
    __shared__ float red_q[64];
    __shared__ __align__(16) unsigned short xpose[4][16 * 64];  // 2KB per wave
    int t = threadIdx.x;
    if (t < 64) { red_s[t] = 0.f; red_q[t] = 0.f; }
    __syncthreads();

    int w = t >> 6, lane = t & 63, l15 = lane & 15, quad = lane >> 4;
    int p = lane >> 2, qq = lane & 3;  // readback role: point p, 32B quarter qq

    short8 aw[4];
    #pragma unroll
    for (int mt = 0; mt < 4; ++mt)
        aw[mt] = *(const short8*)(Wdt + (size_t)(16 * mt + l15) * CIN + quad * 8);

    float s1[16], sq[16];
    #pragma unroll
    for (int e = 0; e < 16; ++e) { s1[e] = 0.f; sq[e] = 0.f; }

    int numTiles = (N + 15) >> 4;
    int stride = gridDim.x * 4;
    int tile = blockIdx.x * 4 + w;

    float4 c0 = make_float4(0.f, 0.f, 0.f, 0.f), c1 = c0;
    {
        int pt = tile * 16 + l15;
        if (tile < numTiles && pt < N) {
            const float4* s = (const float4*)(feats + (size_t)pt * CIN + quad * 8);
            c0 = s[0]; c1 = s[1];
        }
    }

    while (tile < numTiles) {
        int nt = tile + stride;
        float4 n0 = make_float4(0.f, 0.f, 0.f, 0.f), n1 = n0;
        {
            int npt = nt * 16 + l15;
            if (nt < numTiles && npt < N) {
                const float4* s = (const float4*)(feats + (size_t)npt * CIN + quad * 8);
                n0 = s[0]; n1 = s[1];
            }
        }
        union { short8 v; unsigned u[4]; } b;
        b.u[0] = pk2bf(c0.x, c0.y);
        b.u[1] = pk2bf(c0.z, c0.w);
        b.u[2] = pk2bf(c1.x, c1.y);
        b.u[3] = pk2bf(c1.z, c1.w);

        float4v acc[4];
        #pragma unroll
        for (int mt = 0; mt < 4; ++mt)
            acc[mt] = __builtin_amdgcn_mfma_f32_16x16x32_bf16(
                aw[mt], b.v, (float4v){0.f, 0.f, 0.f, 0.f}, 0, 0, 0);

        // wave-local transpose: chunk c = mt*4+quad (8B) at slot c^l15 of row l15
        {
            char* xb = (char*)xpose[w];
            #pragma unroll
            for (int mt = 0; mt < 4; ++mt) {
                uint2 o;
                o.x = pk2bf(acc[mt][0], acc[mt][1]);
                o.y = pk2bf(acc[mt][2], acc[mt][3]);
                *(uint2*)(xb + l15 * 128 + (((mt * 4 + quad) ^ l15) * 8)) = o;
            }
            int pt2 = tile * 16 + p;
            if (pt2 < N) {  // lane stores 32B of row p: chunks 4qq..4qq+3
                uint2 d0 = *(uint2*)(xb + p * 128 + (((qq * 4 + 0) ^ p) * 8));
                uint2 d1 = *(uint2*)(xb + p * 128 + (((qq * 4 + 1) ^ p) * 8));
                uint2 d2 = *(uint2*)(xb + p * 128 + (((qq * 4 + 2) ^ p) * 8));
                uint2 d3 = *(uint2*)(xb + p * 128 + (((qq * 4 + 3) ^ p) * 8));
                uint4 o0 = make_uint4(d0.x, d0.y, d1.x, d1.y);
                uint4 o1 = make_uint4(d2.x, d2.y, d3.x, d3.y);
                *(uint4*)(t_bf + (size_t)pt2 * COUT + qq * 16) = o0;
                *(uint4*)(t_bf + (size_t)pt2 * COUT + qq * 16 + 8) = o1;
            }
        }

        #pragma unroll
        for (int mt = 0; mt < 4; ++mt)
            #pragma unroll
            for (int e = 0; e < 4; ++e) {
                float v = acc[mt][e];
                s1[mt * 4 + e] += v; sq[mt * 4 + e] += v * v;
            }
        c0 = n0; c1 = n1;
        tile = nt;
    }

    #pragma unroll
    for (int m = 1; m <= 8; m <<= 1) {
        #pragma unroll
        for (int e = 0; e < 16; ++e) {
            s1[e] += __shfl_xor(s1[e], m);
            sq[e] += __shfl_xor(sq[e], m);
        }
    }
    if (l15 == 0) {
        #pragma unroll
        for (int e = 0; e < 16; ++e) {
            int ch = (e >> 2) * 16 + quad * 4 + (e & 3);
            atomicAdd(&red_s[ch], s1[e]);
            atomicAdd(&red_q[ch], sq[e]);
        }
    }
    __syncthreads();
    float* dst = red0 + (size_t)(blockIdx.x & 3) * 128;
    if (t < 64)       atomicAdd(&dst[t], red_s[t]);
    else if (t < 128) atomicAdd(&dst[t], red_q[t - 64]);
}

// ---------------------------------------------------------------------------
// Gather-only pool with inlined BN0 finalize; bucket+cnt LDS-staged per block.
// ---------------------------------------------------------------------------
__global__ __launch_bounds__(256) void pool_max_kernel(
    const unsigned short* __restrict__ t_bf,
    const int* __restrict__ cnt, const int* __restrict__ bucket,
    const float* __restrict__ red0, const float* __restrict__ g0,
    const float* __restrict__ b0,
    unsigned short* __restrict__ down_bf, int M, int N)
{
    __shared__ float sc_s[64], sh_s[64];
    __shared__ int bkt_s[16][16];
    __shared__ int cnt_s[16];
    int t = threadIdx.x;
    if (t < 64) {
        float s = 0.f, q2 = 0.f;
        #pragma unroll
        for (int i = 0; i < 4; ++i) { s += red0[i * 128 + t]; q2 += red0[i * 128 + 64 + t]; }
        float m = s / (float)N;
        float var = q2 / (float)N - m * m;
        float sc = g0[t] / sqrtf(var + EPSF);
        sc_s[t] = sc;
        sh_s[t] = b0[t] - m * sc;
    }
    // stage this block's 16 segments' bucket rows (1KB) + cnts, coalesced
    int sb0 = blockIdx.x * 16;
    {
        int j = sb0 * 16 + t;           // 256 consecutive ints
        ((int*)bkt_s)[t] = (j < M * 16) ? bucket[j] : 0;
        if (t < 16) cnt_s[t] = (sb0 + t < M) ? cnt[sb0 + t] : 0;
    }
    __syncthreads();

    int sl = t >> 4, cg = t & 15;
    int s = sb0 + sl;
    if (s >= M) return;
    int n = cnt_s[sl];
    float4 mx = make_float4(-INFINITY, -INFINITY, -INFINITY, -INFINITY);
    float4 mn = make_float4( INFINITY,  INFINITY,  INFINITY,  INFINITY);
    for (int p = 0; p < n; ++p) {
        int idx = bkt_s[sl][p];
        ushort4 v = *(const ushort4*)(t_bf + (size_t)idx * COUT + cg * 4);
        float f0 = bf2f(v.x), f1 = bf2f(v.y), f2 = bf2f(v.z), f3 = bf2f(v.w);
        mx.x = fmaxf(mx.x, f0); mn.x = fminf(mn.x, f0);
        mx.y = fmaxf(mx.y, f1); mn.y = fminf(mn.y, f1);
        mx.z = fmaxf(mx.z, f2); mn.z = fminf(mn.z, f2);
        mx.w = fmaxf(mx.w, f3); mn.w = fminf(mn.w, f3);
    }
    int c0 = cg * 4;
    float scx = sc_s[c0], scy = sc_s[c0 + 1], scz = sc_s[c0 + 2], scw = sc_s[c0 + 3];
    float shx = sh_s[c0], shy = sh_s[c0 + 1], shz = sh_s[c0 + 2], shw = sh_s[c0 + 3];
    ushort4 o;
    o.x = f2bf(eluf(scx * (scx >= 0.f ? mx.x : mn.x) + shx));
    o.y = f2bf(eluf(scy * (scy >= 0.f ? mx.y : mn.y) + shy));
    o.z = f2bf(eluf(scz * (scz >= 0.f ? mx.z : mn.z) + shz));
    o.w = f2bf(eluf(scw * (scw >= 0.f ? mx.w : mn.w) + shw));
    *(ushort4*)(down_bf + (size_t)s * COUT + c0) = o;
}

// o1t = bf16( ELU(scale1*o1b + shift1) ), bf16 in, inlined BN finalize.
__global__ __launch_bounds__(256) void bn_elu_cvt_kernel(
    const unsigned short* __restrict__ o1b, const float* __restrict__ red,
    const float* __restrict__ g, const float* __restrict__ bb,
    unsigned short* __restrict__ o1t, int n4, int M)
{
    __shared__ float sc_s[64], sh_s[64];
    int t = threadIdx.x;
    if (t < 64) {
        float m = red[t] / (float)M;
        float var = red[64 + t] / (float)M - m * m;
        float sc = g[t] / sqrtf(var + EPSF);
        sc_s[t] = sc;
        sh_s[t] = bb[t] - m * sc;
    }
    __syncthreads();
    int i = blockIdx.x * 256 + t;
    if (i < n4) {
        ushort4 v = ((const ushort4*)o1b)[i];
        int c0 = (i & 15) * 4;
        ushort4 o;
        o.x = f2bf(eluf(bf2f(v.x) * sc_s[c0]     + sh_s[c0]));
        o.y = f2bf(eluf(bf2f(v.y) * sc_s[c0 + 1] + sh_s[c0 + 1]));
        o.z = f2bf(eluf(bf2f(v.z) * sc_s[c0 + 2] + sh_s[c0 + 2]));
        o.w = f2bf(eluf(bf2f(v.w) * sc_s[c0 + 3] + sh_s[c0 + 3]));
        ((ushort4*)o1t)[i] = o;
    }
}

// out = elu( elu(scale2*raw + shift2) + down ), bf16 raw in, inlined finalize.
__global__ __launch_bounds__(256) void final_kernel(
    float* __restrict__ out, const unsigned short* __restrict__ o2b,
    const unsigned short* __restrict__ down_bf,
    const float* __restrict__ red, const float* __restrict__ g,
    const float* __restrict__ bb, int n4, int M)
{
    __shared__ float sc_s[64], sh_s[64];
    int t = threadIdx.x;
    if (t < 64) {
        float m = red[t] / (float)M;
        float var = red[64 + t] / (float)M - m * m;
        float sc = g[t] / sqrtf(var + EPSF);
        sc_s[t] = sc;
        sh_s[t] = bb[t] - m * sc;
    }
    __syncthreads();
    int i = blockIdx.x * 256 + t;
    if (i < n4) {
        ushort4 v = ((const ushort4*)o2b)[i];
        ushort4 d = ((const ushort4*)down_bf)[i];
        int c0 = (i & 15) * 4;
        float4 o;
        o.x = eluf(eluf(bf2f(v.x) * sc_s[c0]     + sh_s[c0])     + bf2f(d.x));
        o.y = eluf(eluf(bf2f(v.y) * sc_s[c0 + 1] + sh_s[c0 + 1]) + bf2f(d.y));
        o.z = eluf(eluf(bf2f(v.z) * sc_s[c0 + 2] + sh_s[c0 + 2]) + bf2f(d.z));
        o.w = eluf(eluf(bf2f(v.w) * sc_s[c0 + 3] + sh_s[c0 + 3]) + bf2f(d.w));
        ((float4*)out)[i] = o;
    }
}

// ---------------------------------------------------------------------------
// MFMA implicit-GEMM sparse conv (round-10 best, measured 473.7us total):
// async staging via global_load_lds (no dest regs -> loads stay in flight
// across compute; the compiler cannot sink them, unlike reg-staged prefetch,
// rounds 6-8), source-side XOR swizzle (m173), wave-linear LDS dest, zero
// row M for missing neighbors, 256x64 tile, 512 thr, 80KB LDS (2 blocks/CU),
// XCD-chunked bijective block swizzle (m204), fused BN stats, raw bf16 out.
// Counted-vmcnt dual-barrier variant (round 11) measured -7us: rejected.
// ---------------------------------------------------------------------------
__global__ __launch_bounds__(512, 4) void conv_mfma_kernel(
    const unsigned short* __restrict__ in,   // (M+1) x 64, row M = zeros
    const unsigned short* __restrict__ Wt,
    const int* __restrict__ nbrT, int M,
    unsigned short* __restrict__ outb, float* __restrict__ red_out)
{
    __shared__ __align__(16) unsigned short A_lds[2][256 * 64];  // 64 KB
    __shared__ __align__(16) unsigned short W_lds[2][64 * 64];   // 16 KB
    int t = threadIdx.x;

    // XCD-chunked bijective remap (m204)
    int nwg = gridDim.x;
    int q = nwg >> 3, r = nwg & 7;
    int xcd = blockIdx.x & 7, pos = blockIdx.x >> 3;
    int sb = (xcd < r ? xcd * (q + 1) : r * (q + 1) + (xcd - r) * q) + pos;
    int base = sb * 256;

    int w = t >> 6, lane = t & 63, l15 = lane & 15, quad = lane >> 4;
    int ar8 = lane >> 3, ac = lane & 7;  // staging: 8 lanes/row, slot ac

    float4v acc[2][4];
    #pragma unroll
    for (int s = 0; s < 2; ++s)
        #pragma unroll
        for (int n = 0; n < 4; ++n)
            acc[s][n] = (float4v){0.f, 0.f, 0.f, 0.f};

    // resolve gather row (zero row M for missing/tail) for 4 A-chunks of this wave
    auto LOADIDX = [&](int k, int* e) {
        #pragma unroll
        for (int i = 0; i < 4; ++i) {
            int rr = (w << 5) + (i << 3) + ar8;
            int j = base + rr;
            int idx = nbrT[(size_t)k * M + (j < M ? j : 0)];
            e[i] = (j < M && idx >= 0) ? idx : M;
        }
    };
    // stage A (32KB) + W (8KB) for one k-offset into buffer buf, async.
    auto STAGE = [&](int buf, const int* e, int kw) {
        unsigned short* An = A_lds[buf];
        unsigned short* Wn = W_lds[buf];
        #pragma unroll
        for (int i = 0; i < 4; ++i) {
            int rr = (w << 5) + (i << 3) + ar8;
            gload_lds16(in + (size_t)e[i] * COUT + ((ac ^ (rr & 7)) * 8),
                        An + (w << 11) + (i << 9));
        }
        int wr = (w << 3) + ar8;
        gload_lds16(Wt + (size_t)kw * (COUT * COUT) + wr * COUT + ((ac ^ (wr & 7)) * 8),
                    Wn + (w << 9));
    };

    int eC[4], eN[4];
    LOADIDX(0, eC);
    STAGE(0, eC, 0);
    LOADIDX(1, eC);   // indices for k=1 (used next)
    __syncthreads();

    for (int k = 0; k < KVOL; ++k) {
        bool pf = (k + 1 < KVOL);
        if (pf) {
            STAGE((k + 1) & 1, eC, k + 1);            // async, in flight across compute
            if (k + 2 < KVOL) LOADIDX(k + 2, eN);     // indices for next STAGE
        }
        __builtin_amdgcn_sched_barrier(0);

        // ---- compute on buf[k&1] ----
        const unsigned short* Ab = A_lds[k & 1];
        const unsigned short* Wb = W_lds[k & 1];
        #pragma unroll
        for (int kk = 0; kk < 64; kk += 32) {
            int slb = quad + (kk >> 3);
            int r0 = 32 * w + l15;
            short8 a0 = *(const short8*)(Ab + r0 * 64 + ((slb ^ (r0 & 7)) * 8));
            int r1 = r0 + 16;
            short8 a1 = *(const short8*)(Ab + r1 * 64 + ((slb ^ (r1 & 7)) * 8));
            #pragma unroll
            for (int n = 0; n < 4; ++n) {
                int rb = 16 * n + l15;
                short8 b = *(const short8*)(Wb + rb * 64 + ((slb ^ (rb & 7)) * 8));
                acc[0][n] = __builtin_amdgcn_mfma_f32_16x16x32_bf16(a0, b, acc[0][n], 0, 0, 0);
                acc[1][n] = __builtin_amdgcn_mfma_f32_16x16x32_bf16(a1, b, acc[1][n], 0, 0, 0);
            }
        }

        if (pf) {
            #pragma unroll
            for (int i = 0; i < 4; ++i) eC[i] = eN[i];
        }
        __syncthreads();  // drains the in-flight global_load_lds + syncs buffers
    }

    // stores (C/D layout: col=lane&15, row=quad*4+reg), raw bf16
    #pragma unroll
    for (int s = 0; s < 2; ++s) {
        int row = base + 32 * w + 16 * s + quad * 4;
        #pragma unroll
        for (int n = 0; n < 4; ++n) {
            int c = 16 * n + l15;
            #pragma unroll
            for (int e = 0; e < 4; ++e)
                if (row + e < M)
                    outb[(size_t)(row + e) * COUT + c] = f2bf(acc[s][n][e]);
        }
    }

    // fused BN stats (rows >= M are exact zeros); scratch aliased into W_lds
    float* red_s = (float*)(W_lds[0]);
    float* red_q = red_s + 64;
    if (t < 128) red_s[t] = 0.f;
    __syncthreads();
    #pragma unroll
    for (int n = 0; n < 4; ++n) {
        float s1 = 0.f, sq = 0.f;
        #pragma unroll
        for (int s = 0; s < 2; ++s)
            #pragma unroll
            for (int e = 0; e < 4; ++e) { float v = acc[s][n][e]; s1 += v; sq += v * v; }
        s1 += __shfl_xor(s1, 16); sq += __shfl_xor(sq, 16);
        s1 += __shfl_xor(s1, 32); sq += __shfl_xor(sq, 32);
        if (quad == 0) {
            atomicAdd(&red_s[16 * n + l15], s1);
            atomicAdd(&red_q[16 * n + l15], sq);
        }
    }
    __syncthreads();
    if (t < 64)       atomicAdd(&red_out[t], red_s[t]);
    else if (t < 128) atomicAdd(&red_out[t], red_q[t - 64]);
}

extern "C" void kernel_launch(void* const* d_in, const int* in_sizes, int n_in,
                              void* d_out, int out_size, void* d_ws, size_t ws_size,
                              hipStream_t stream)
{
    (void)n_in; (void)ws_size;
    const float* feats    = (const float*)d_in[0];
    const float* Wd       = (const float*)d_in[1];
    const float* g0       = (const float*)d_in[2];
    const float* b0       = (const float*)d_in[3];
    const float* W1       = (const float*)d_in[4];
    const float* g1       = (const float*)d_in[5];
    const float* b1       = (const float*)d_in[6];
    const float* W2       = (const float*)d_in[7];
    const float* g2       = (const float*)d_in[8];
    const float* b2       = (const float*)d_in[9];
    const int*   pool_seg = (const int*)d_in[10];
    const int*   conv_in  = (const int*)d_in[11];
    const int*   conv_out = (const int*)d_in[12];

    int N = in_sizes[0] / CIN;
    int M = out_size / COUT;
    int L = in_sizes[11] / KVOL;

    char* ws = (char*)d_ws;
    size_t off = 0;
    auto alloc = [&](size_t bytes) -> void* {
        void* p = ws + off;
        off = (off + bytes + 255) & ~(size_t)255;
        return p;
    };
    unsigned short* down_bf = (unsigned short*)alloc((size_t)(M + 1) * COUT * 2);
    unsigned short* o1b     = (unsigned short*)alloc((size_t)M * COUT * 2);
    unsigned short* o1t     = (unsigned short*)alloc((size_t)(M + 1) * COUT * 2);
    unsigned short* o2b     = (unsigned short*)alloc((size_t)M * COUT * 2);
    unsigned short* t_bf    = (unsigned short*)alloc((size_t)N * COUT * 2);
    int*            nbrT    = (int*)alloc((size_t)KVOL * M * 4);
    unsigned short* Wt1     = (unsigned short*)alloc((size_t)KVOL * COUT * COUT * 2);
    unsigned short* Wt2     = (unsigned short*)alloc((size_t)KVOL * COUT * COUT * 2);
    unsigned short* Wdt     = (unsigned short*)alloc((size_t)CIN * COUT * 2);
    int*            bucket  = (int*)alloc((size_t)(M + 16) * 16 * 4);
    int*            cnt     = (int*)alloc((size_t)M * 4);         // cnt and red are
    float*          red     = (float*)alloc((size_t)768 * 4);     // adjacent: 1 memset
    float* red0 = red, *red1 = red + 512, *red2 = red + 640;

    hipMemsetAsync(nbrT, 0xFF, (size_t)KVOL * M * 4, stream);     // -1 = missing nbr
    hipMemsetAsync(cnt, 0, (size_t)((char*)(red + 768) - (char*)cnt), stream);
    hipMemsetAsync(down_bf + (size_t)M * COUT, 0, COUT * 2, stream);  // zero row M
    hipMemsetAsync(o1t + (size_t)M * COUT, 0, COUT * 2, stream);      // zero row M

    int nbB = (N + 255) / 256, nbL = (L + 255) / 256;
    prep_kernel<<<55 + nbB + nbL * KVOL, 256, 0, stream>>>(
        W1, W2, Wd, Wt1, Wt2, Wdt, pool_seg, cnt, bucket, N,
        conv_out, conv_in, nbrT, L, M, nbB, nbL);
    gemm_t_kernel<<<1024, 256, 0, stream>>>(feats, Wdt, N, t_bf, red0);
    pool_max_kernel<<<(M + 15) / 16, 256, 0, stream>>>(
        t_bf, cnt, bucket, red0, g0, b0, down_bf, M, N);

    int cblocks = (M + 255) / 256;
    int n4 = (M * COUT) / 4;
    // conv1: bf16 in (down), RAW bf16 out + BN1 stats
    conv_mfma_kernel<<<cblocks, 512, 0, stream>>>(down_bf, Wt1, nbrT, M, o1b, red1);
    // BN1+ELU elementwise (bf16 -> bf16)
    bn_elu_cvt_kernel<<<(n4 + 255) / 256, 256, 0, stream>>>(o1b, red1, g1, b1, o1t, n4, M);
    // conv2: RAW bf16 out + BN2 stats
    conv_mfma_kernel<<<cblocks, 512, 0, stream>>>(o1t, Wt2, nbrT, M, o2b, red2);
    // final: BN2+ELU + residual + ELU, f32 out
    final_kernel<<<(n4 + 255) / 256, 256, 0, stream>>>(
        (float*)d_out, o2b, down_bf, red2, g2, b2, n4, M);
}